// Round 5
// baseline (394.842 us; speedup 1.0000x reference)
//
#include <hip/hip_runtime.h>
#include <math.h>

#define N_CELLS 2048
#define D_IN 512
#define D_HID 1024
#define D_OUT 512

typedef __attribute__((ext_vector_type(8))) short bf16x8;
typedef __attribute__((ext_vector_type(4))) float f32x4;
typedef __attribute__((ext_vector_type(4))) short short4v;

#define MFMA16(a, b, c) __builtin_amdgcn_mfma_f32_16x16x32_bf16(a, b, c, 0, 0, 0)

__device__ __forceinline__ short f2bf(float f) {
  union { float f; unsigned u; } v; v.f = f;
  unsigned r = (v.u + 0x7FFFu + ((v.u >> 16) & 1u)) >> 16;
  return (short)r;
}

// ---------------- prep: all weight transposes in ONE launch ----------------
__global__ __launch_bounds__(256) void k_transpose_all(
    const float* __restrict__ w0, const float* __restrict__ w1,
    const float* __restrict__ w2, const float* __restrict__ w3,
    short* __restrict__ t0, short* __restrict__ t1,
    short* __restrict__ t2, short* __restrict__ t3,
    const float* __restrict__ ea_wr, const float* __restrict__ eg_wr,
    const float* __restrict__ ea_wi, const float* __restrict__ eg_wi,
    short* __restrict__ wdrT, short* __restrict__ wdiT, short* __restrict__ wdnT) {
  const int k0 = blockIdx.x * 32, n0 = blockIdx.y * 32;
  const int c = threadIdx.x & 31, r4 = threadIdx.x >> 5;
  if (blockIdx.z < 4) {
    const float* w = (blockIdx.z == 0) ? w0 : (blockIdx.z == 1) ? w1
                   : (blockIdx.z == 2) ? w2 : w3;
    short* wT = (blockIdx.z == 0) ? t0 : (blockIdx.z == 1) ? t1
              : (blockIdx.z == 2) ? t2 : t3;
    __shared__ float t[32][33];
#pragma unroll
    for (int i = 0; i < 4; ++i) {
      int kl = r4 * 4 + i;
      int k = k0 + kl;
      int srcrow = (k < 512) ? k : k + 1;
      t[kl][c] = w[(size_t)srcrow * D_HID + n0 + c];
    }
    __syncthreads();
#pragma unroll
    for (int i = 0; i < 4; ++i) {
      int nl = r4 * 4 + i;
      wT[(size_t)(n0 + nl) * 1536 + k0 + c] = f2bf(t[c][nl]);
    }
  } else {
    if (blockIdx.x >= 32 || blockIdx.y >= 16) return;
    __shared__ float tr[32][33], ti[32][33];
#pragma unroll
    for (int i = 0; i < 4; ++i) {
      int kl = r4 * 4 + i;
      int src = (512 + k0 + kl) * D_OUT + n0 + c;
      tr[kl][c] = ea_wr[src] - eg_wr[src];
      ti[kl][c] = ea_wi[src] - eg_wi[src];
    }
    __syncthreads();
#pragma unroll
    for (int i = 0; i < 4; ++i) {
      int nl = r4 * 4 + i;
      int dst = (n0 + nl) * D_HID + k0 + c;
      float dr = tr[c][nl], di = ti[c][nl];
      wdrT[dst] = f2bf(dr);
      wdiT[dst] = f2bf(di);
      wdnT[dst] = f2bf(-di);
    }
  }
}

// h fp32 -> bf16 + |h| into gatesA cols 512..1535 ; also zero tens
__global__ __launch_bounds__(256) void k_prep_h(
    const float* __restrict__ h_re, const float* __restrict__ h_im,
    short* __restrict__ hbre, short* __restrict__ hbim, short* __restrict__ gatesA,
    float* __restrict__ tens) {
  if (threadIdx.x == 0) tens[blockIdx.x] = 0.f;
  int idx4 = (blockIdx.x * 256 + threadIdx.x) * 4;
  int m = idx4 >> 10, n = idx4 & 1023;
  float4 hr = *(const float4*)&h_re[idx4];
  float4 hi = *(const float4*)&h_im[idx4];
  short4v br, bi, bm;
  br.x = f2bf(hr.x); br.y = f2bf(hr.y); br.z = f2bf(hr.z); br.w = f2bf(hr.w);
  bi.x = f2bf(hi.x); bi.y = f2bf(hi.y); bi.z = f2bf(hi.z); bi.w = f2bf(hi.w);
  bm.x = f2bf(sqrtf(hr.x * hr.x + hi.x * hi.x));
  bm.y = f2bf(sqrtf(hr.y * hr.y + hi.y * hi.y));
  bm.z = f2bf(sqrtf(hr.z * hr.z + hi.z * hi.z));
  bm.w = f2bf(sqrtf(hr.w * hr.w + hi.w * hi.w));
  *(short4v*)&hbre[idx4] = br;
  *(short4v*)&hbim[idx4] = bi;
  *(short4v*)&gatesA[(size_t)m * 1536 + 512 + n] = bm;
}

// ---------------- bias from x: split-K two-stage ----------------
__global__ __launch_bounds__(256) void k_bias_part(
    const float* __restrict__ x,
    const float* __restrict__ ea_wr, const float* __restrict__ ea_wi,
    const float* __restrict__ eg_wr, const float* __restrict__ eg_wi,
    float* __restrict__ bpartr, float* __restrict__ bparti) {
  int n = blockIdx.x * 256 + threadIdx.x;
  int kc = blockIdx.y;
  float sr = 0.f, si = 0.f;
  for (int i = 0; i < 64; ++i) {
    int k = kc * 64 + i;
    float xv = x[k];
    int idx = k * D_OUT + n;
    sr += xv * (ea_wr[idx] - eg_wr[idx]);
    si += xv * (ea_wi[idx] - eg_wi[idx]);
  }
  bpartr[kc * D_OUT + n] = sr;
  bparti[kc * D_OUT + n] = si;
}

__global__ __launch_bounds__(256) void k_bias_red(
    const float* __restrict__ bpartr, const float* __restrict__ bparti,
    const float* __restrict__ ea_br, const float* __restrict__ ea_bi,
    const float* __restrict__ eg_br, const float* __restrict__ eg_bi,
    float* __restrict__ bias_re, float* __restrict__ bias_im) {
  int n = blockIdx.x * 256 + threadIdx.x;
  float sr = 0.f, si = 0.f;
#pragma unroll
  for (int kc = 0; kc < 8; ++kc) { sr += bpartr[kc * D_OUT + n]; si += bparti[kc * D_OUT + n]; }
  float brd = ea_br[n] - eg_br[n];
  float bid = ea_bi[n] - eg_bi[n];
  bias_re[n] = sr + brd - bid;
  bias_im[n] = si + brd + bid;
}

// ---------------- MFMA GEMM 1: complex engine, barrier-free direct-register ----
// wave tile 32m x 32n, block = 4 waves stacked in m (128x32), grid (16,16).
__global__ __launch_bounds__(256) void k_engine(
    const short* __restrict__ hbre, const short* __restrict__ hbim,
    const short* __restrict__ wdrT, const short* __restrict__ wdiT,
    const short* __restrict__ wdnT,
    const float* __restrict__ bias_re, const float* __restrict__ bias_im,
    float* __restrict__ ore, float* __restrict__ oim,
    short* __restrict__ gatesA, short* __restrict__ candAre, short* __restrict__ candAim,
    float* __restrict__ tens) {
  const int tid = threadIdx.x, wid = tid >> 6, lane = tid & 63;
  const int quad = lane >> 4, lcol = lane & 15;
  const int m0 = blockIdx.x * 128 + wid * 32;
  const int n0 = blockIdx.y * 32;
  const short* pAr0 = hbre + (size_t)(m0 + lcol) * D_HID + quad * 8;
  const short* pAr1 = hbre + (size_t)(m0 + 16 + lcol) * D_HID + quad * 8;
  const short* pAi0 = hbim + (size_t)(m0 + lcol) * D_HID + quad * 8;
  const short* pAi1 = hbim + (size_t)(m0 + 16 + lcol) * D_HID + quad * 8;
  const short* pBr0 = wdrT + (size_t)(n0 + lcol) * D_HID + quad * 8;
  const short* pBr1 = wdrT + (size_t)(n0 + 16 + lcol) * D_HID + quad * 8;
  const short* pBi0 = wdiT + (size_t)(n0 + lcol) * D_HID + quad * 8;
  const short* pBi1 = wdiT + (size_t)(n0 + 16 + lcol) * D_HID + quad * 8;
  const short* pBn0 = wdnT + (size_t)(n0 + lcol) * D_HID + quad * 8;
  const short* pBn1 = wdnT + (size_t)(n0 + 16 + lcol) * D_HID + quad * 8;
  f32x4 accre[2][2], accim[2][2];
#pragma unroll
  for (int mt = 0; mt < 2; ++mt)
#pragma unroll
    for (int nt = 0; nt < 2; ++nt) {
      accre[mt][nt] = (f32x4){0.f, 0.f, 0.f, 0.f};
      accim[mt][nt] = (f32x4){0.f, 0.f, 0.f, 0.f};
    }
#pragma unroll 4
  for (int kk = 0; kk < 32; ++kk) {
    bf16x8 ar[2], ai[2], br[2], bi[2], bn[2];
    ar[0] = *(const bf16x8*)pAr0; pAr0 += 32;
    ar[1] = *(const bf16x8*)pAr1; pAr1 += 32;
    ai[0] = *(const bf16x8*)pAi0; pAi0 += 32;
    ai[1] = *(const bf16x8*)pAi1; pAi1 += 32;
    br[0] = *(const bf16x8*)pBr0; pBr0 += 32;
    br[1] = *(const bf16x8*)pBr1; pBr1 += 32;
    bi[0] = *(const bf16x8*)pBi0; pBi0 += 32;
    bi[1] = *(const bf16x8*)pBi1; pBi1 += 32;
    bn[0] = *(const bf16x8*)pBn0; pBn0 += 32;
    bn[1] = *(const bf16x8*)pBn1; pBn1 += 32;
#pragma unroll
    for (int mt = 0; mt < 2; ++mt)
#pragma unroll
      for (int nt = 0; nt < 2; ++nt) {
        accre[mt][nt] = MFMA16(ar[mt], br[nt], accre[mt][nt]);
        accre[mt][nt] = MFMA16(ai[mt], bn[nt], accre[mt][nt]);
        accim[mt][nt] = MFMA16(ar[mt], bi[nt], accim[mt][nt]);
        accim[mt][nt] = MFMA16(ai[mt], br[nt], accim[mt][nt]);
      }
  }
#pragma unroll
  for (int mt = 0; mt < 2; ++mt)
#pragma unroll
    for (int r = 0; r < 4; ++r) {
      int m = m0 + mt * 16 + quad * 4 + r;
      float t = 0.f;
#pragma unroll
      for (int nt = 0; nt < 2; ++nt) {
        int n = n0 + nt * 16 + lcol;
        float cre = accre[mt][nt][r] + bias_re[n];
        float cim = accim[mt][nt][r] + bias_im[n];
        t += cre * cre + cim * cim;
        ore[(size_t)m * D_OUT + n] = cre;
        oim[(size_t)m * D_OUT + n] = cim;
        gatesA[(size_t)m * 1536 + n] = f2bf(sqrtf(cre * cre + cim * cim));
        candAre[(size_t)m * 1536 + n] = f2bf(cre);
        candAim[(size_t)m * 1536 + n] = f2bf(cim);
      }
#pragma unroll
      for (int off = 1; off < 16; off <<= 1) t += __shfl_xor(t, off);
      if (lcol == 0) atomicAdd(&tens[m], t * (1.f / 512.f));
    }
}

// ---------------- MFMA GEMM 2: gates (z/r via blockIdx.z), barrier-free ----
// wave tile 32m x 64n, block = 4 waves stacked in m (128x64), grid (16,16,2).
__global__ __launch_bounds__(256) void k_gates(
    const short* __restrict__ gatesA,
    const short* __restrict__ gzwT, const short* __restrict__ grwT,
    const float* __restrict__ gz_w, const float* __restrict__ gz_b,
    const float* __restrict__ gr_w, const float* __restrict__ gr_b,
    const float* __restrict__ tens,
    const float* __restrict__ h_re, const float* __restrict__ h_im,
    float* __restrict__ zbuf,
    short* __restrict__ candAre, short* __restrict__ candAim) {
  const int is_z = (blockIdx.z == 0);
  const short* Bt = is_z ? gzwT : grwT;
  const int tid = threadIdx.x, wid = tid >> 6, lane = tid & 63;
  const int quad = lane >> 4, lcol = lane & 15;
  const int m0 = blockIdx.x * 128 + wid * 32;
  const int n0 = blockIdx.y * 64;
  const short* pA0 = gatesA + (size_t)(m0 + lcol) * 1536 + quad * 8;
  const short* pA1 = gatesA + (size_t)(m0 + 16 + lcol) * 1536 + quad * 8;
  const short* pB0 = Bt + (size_t)(n0 + lcol) * 1536 + quad * 8;
  const short* pB1 = Bt + (size_t)(n0 + 16 + lcol) * 1536 + quad * 8;
  const short* pB2 = Bt + (size_t)(n0 + 32 + lcol) * 1536 + quad * 8;
  const short* pB3 = Bt + (size_t)(n0 + 48 + lcol) * 1536 + quad * 8;
  f32x4 acc[2][4];
#pragma unroll
  for (int mt = 0; mt < 2; ++mt)
#pragma unroll
    for (int nt = 0; nt < 4; ++nt) acc[mt][nt] = (f32x4){0.f, 0.f, 0.f, 0.f};
#pragma unroll 4
  for (int kk = 0; kk < 48; ++kk) {
    bf16x8 a0 = *(const bf16x8*)pA0; pA0 += 32;
    bf16x8 a1 = *(const bf16x8*)pA1; pA1 += 32;
    bf16x8 b0 = *(const bf16x8*)pB0; pB0 += 32;
    bf16x8 b1 = *(const bf16x8*)pB1; pB1 += 32;
    bf16x8 b2 = *(const bf16x8*)pB2; pB2 += 32;
    bf16x8 b3 = *(const bf16x8*)pB3; pB3 += 32;
    acc[0][0] = MFMA16(a0, b0, acc[0][0]);
    acc[0][1] = MFMA16(a0, b1, acc[0][1]);
    acc[0][2] = MFMA16(a0, b2, acc[0][2]);
    acc[0][3] = MFMA16(a0, b3, acc[0][3]);
    acc[1][0] = MFMA16(a1, b0, acc[1][0]);
    acc[1][1] = MFMA16(a1, b1, acc[1][1]);
    acc[1][2] = MFMA16(a1, b2, acc[1][2]);
    acc[1][3] = MFMA16(a1, b3, acc[1][3]);
  }
#pragma unroll
  for (int mt = 0; mt < 2; ++mt)
#pragma unroll
    for (int nt = 0; nt < 4; ++nt)
#pragma unroll
      for (int r = 0; r < 4; ++r) {
        int m = m0 + mt * 16 + quad * 4 + r;
        int n = n0 + nt * 16 + lcol;
        float tv = tens[m];
        if (is_z) {
          float zp = acc[mt][nt][r] + gz_b[n] + tv * gz_w[(size_t)512 * D_HID + n];
          zbuf[(size_t)m * D_HID + n] = 1.f / (1.f + expf(-zp));
        } else {
          float rp = acc[mt][nt][r] + gr_b[n] + tv * gr_w[(size_t)512 * D_HID + n];
          float rr = 1.f / (1.f + expf(-rp));
          candAre[(size_t)m * 1536 + 512 + n] = f2bf(rr * h_re[(size_t)m * D_HID + n]);
          candAim[(size_t)m * 1536 + 512 + n] = f2bf(rr * h_im[(size_t)m * D_HID + n]);
        }
      }
}

// ---------------- MFMA GEMM 3: candidate + GRU blend, barrier-free ----
__global__ __launch_bounds__(256) void k_cand(
    const short* __restrict__ candAre, const short* __restrict__ candAim,
    const short* __restrict__ ghrwT, const short* __restrict__ ghiwT,
    const float* __restrict__ ghr_b, const float* __restrict__ ghi_b,
    const float* __restrict__ ghr_w,
    const float* __restrict__ tens, const float* __restrict__ zbuf,
    const float* __restrict__ h_re, const float* __restrict__ h_im,
    float* __restrict__ nhre, float* __restrict__ nhim) {
  const int is_re = (blockIdx.z == 0);
  const short* A = is_re ? candAre : candAim;
  const short* Bt = is_re ? ghrwT : ghiwT;
  const float* bias = is_re ? ghr_b : ghi_b;
  const float* h = is_re ? h_re : h_im;
  float* outp = is_re ? nhre : nhim;
  const int tid = threadIdx.x, wid = tid >> 6, lane = tid & 63;
  const int quad = lane >> 4, lcol = lane & 15;
  const int m0 = blockIdx.x * 128 + wid * 32;
  const int n0 = blockIdx.y * 64;
  const short* pA0 = A + (size_t)(m0 + lcol) * 1536 + quad * 8;
  const short* pA1 = A + (size_t)(m0 + 16 + lcol) * 1536 + quad * 8;
  const short* pB0 = Bt + (size_t)(n0 + lcol) * 1536 + quad * 8;
  const short* pB1 = Bt + (size_t)(n0 + 16 + lcol) * 1536 + quad * 8;
  const short* pB2 = Bt + (size_t)(n0 + 32 + lcol) * 1536 + quad * 8;
  const short* pB3 = Bt + (size_t)(n0 + 48 + lcol) * 1536 + quad * 8;
  f32x4 acc[2][4];
#pragma unroll
  for (int mt = 0; mt < 2; ++mt)
#pragma unroll
    for (int nt = 0; nt < 4; ++nt) acc[mt][nt] = (f32x4){0.f, 0.f, 0.f, 0.f};
#pragma unroll 4
  for (int kk = 0; kk < 48; ++kk) {
    bf16x8 a0 = *(const bf16x8*)pA0; pA0 += 32;
    bf16x8 a1 = *(const bf16x8*)pA1; pA1 += 32;
    bf16x8 b0 = *(const bf16x8*)pB0; pB0 += 32;
    bf16x8 b1 = *(const bf16x8*)pB1; pB1 += 32;
    bf16x8 b2 = *(const bf16x8*)pB2; pB2 += 32;
    bf16x8 b3 = *(const bf16x8*)pB3; pB3 += 32;
    acc[0][0] = MFMA16(a0, b0, acc[0][0]);
    acc[0][1] = MFMA16(a0, b1, acc[0][1]);
    acc[0][2] = MFMA16(a0, b2, acc[0][2]);
    acc[0][3] = MFMA16(a0, b3, acc[0][3]);
    acc[1][0] = MFMA16(a1, b0, acc[1][0]);
    acc[1][1] = MFMA16(a1, b1, acc[1][1]);
    acc[1][2] = MFMA16(a1, b2, acc[1][2]);
    acc[1][3] = MFMA16(a1, b3, acc[1][3]);
  }
#pragma unroll
  for (int mt = 0; mt < 2; ++mt)
#pragma unroll
    for (int nt = 0; nt < 4; ++nt)
#pragma unroll
      for (int r = 0; r < 4; ++r) {
        int m = m0 + mt * 16 + quad * 4 + r;
        int n = n0 + nt * 16 + lcol;
        float pre = acc[mt][nt][r] + bias[n];
        if (is_re) pre += tens[m] * ghr_w[(size_t)512 * D_HID + n];
        float cand = tanhf(pre);
        float z = zbuf[(size_t)m * D_HID + n];
        float hv = h[(size_t)m * D_HID + n];
        outp[(size_t)m * D_HID + n] = (1.f - z) * hv + z * cand;
      }
}

// ---------------- faction sync: two-stage ----------------
__global__ __launch_bounds__(256) void k_fsum_part(
    const float* __restrict__ nhre, const float* __restrict__ nhim,
    float* __restrict__ fpart) {
  int f = blockIdx.x >> 3, rc = blockIdx.x & 7, comp = blockIdx.y;
  const float* src = comp ? nhim : nhre;
  int row0 = f * 256 + rc * 32;
#pragma unroll
  for (int nc = 0; nc < 4; ++nc) {
    int n = nc * 256 + threadIdx.x;
    float s = 0.f;
    const float* base = src + (size_t)row0 * D_HID + n;
    for (int j = 0; j < 32; ++j) s += base[(size_t)j * D_HID];
    fpart[((size_t)comp * 64 + blockIdx.x) * D_HID + n] = s;
  }
}

__global__ __launch_bounds__(256) void k_fsum_red(
    const float* __restrict__ fpart,
    float* __restrict__ fsre, float* __restrict__ fsim,
    float* __restrict__ gre, float* __restrict__ gim) {
  int n = blockIdx.x * 256 + threadIdx.x;
  int comp = blockIdx.y;
  float* fs = comp ? fsim : fsre;
  float* g = comp ? gim : gre;
  float gsum = 0.f;
#pragma unroll
  for (int f = 0; f < 8; ++f) {
    float sf = 0.f;
#pragma unroll
    for (int rc = 0; rc < 8; ++rc)
      sf += fpart[((size_t)comp * 64 + f * 8 + rc) * D_HID + n];
    fs[f * D_HID + n] = sf;
    gsum += sf;
  }
  g[n] = gsum * (1.f / 2048.f);
}

__global__ __launch_bounds__(256) void k_sync(
    float* __restrict__ nhre, float* __restrict__ nhim,
    const float* __restrict__ fsre, const float* __restrict__ fsim,
    const float* __restrict__ gre, const float* __restrict__ gim,
    const int* __restrict__ step) {
  int idx = blockIdx.x * 256 + threadIdx.x;
  int m = idx >> 10, n = idx & 1023;
  int f = m >> 8;
  float vr = nhre[idx], vi = nhim[idx];
  vr = 0.85f * vr + 0.15f * (fsre[f * D_HID + n] * (1.f / 256.f));
  vi = 0.85f * vi + 0.15f * (fsim[f * D_HID + n] * (1.f / 256.f));
  if (step[0] > 5 && (m & 255) < 64) {
    vr = 0.85f * vr + 0.15f * gre[n];
    vi = 0.85f * vi + 0.15f * gim[n];
  }
  nhre[idx] = vr;
  nhim[idx] = vi;
}

// ---------------- softmax stats ----------------
__global__ __launch_bounds__(1024) void k_stats(
    const float* __restrict__ tens, float* __restrict__ wsoft,
    float* __restrict__ meanT_out) {
  __shared__ float red[16];
  __shared__ float s_max, s_sum;
  int tid = threadIdx.x;
  int wid = tid >> 6, lane = tid & 63;
  float a = tens[tid], b = tens[tid + 1024];
  float mx = fmaxf(a, b);
  for (int off = 32; off; off >>= 1) mx = fmaxf(mx, __shfl_down(mx, off));
  if (lane == 0) red[wid] = mx;
  __syncthreads();
  if (tid == 0) {
    float m2 = red[0];
    for (int i = 1; i < 16; ++i) m2 = fmaxf(m2, red[i]);
    s_max = m2;
  }
  __syncthreads();
  float mxv = s_max;
  float ea = expf(a - mxv), eb = expf(b - mxv);
  float se = ea + eb;
  for (int off = 32; off; off >>= 1) se += __shfl_down(se, off);
  __syncthreads();
  if (lane == 0) red[wid] = se;
  __syncthreads();
  if (tid == 0) {
    float s2 = 0.f;
    for (int i = 0; i < 16; ++i) s2 += red[i];
    s_sum = s2;
  }
  __syncthreads();
  float inv = 1.f / s_sum;
  wsoft[tid] = ea * inv;
  wsoft[tid + 1024] = eb * inv;
  float st = a + b;
  for (int off = 32; off; off >>= 1) st += __shfl_down(st, off);
  __syncthreads();
  if (lane == 0) red[wid] = st;
  __syncthreads();
  if (tid == 0) {
    float s2 = 0.f;
    for (int i = 0; i < 16; ++i) s2 += red[i];
    meanT_out[0] = s2 * (1.f / 2048.f);
  }
}

// ---------------- combine stage1 ----------------
__global__ __launch_bounds__(256) void k_comb_part(
    const float* __restrict__ ore, const float* __restrict__ oim,
    const float* __restrict__ wsoft, float* __restrict__ cpart) {
  int j = blockIdx.x * 256 + threadIdx.x;
  int mc = blockIdx.y;
  const float* src = (j < 512) ? ore : oim;
  int col = j & 511;
  float s = 0.f;
  for (int i = 0; i < 128; ++i) {
    int m = mc * 128 + i;
    s += wsoft[m] * src[(size_t)m * D_OUT + col];
  }
  cpart[(size_t)mc * 1024 + j] = s;
}

// ---------------- pred stage1 (comb reduction fused in) ----------------
__global__ __launch_bounds__(256) void k_pred_part(
    const float* __restrict__ cpart, const float* __restrict__ oh_w,
    float* __restrict__ ppart) {
  __shared__ float combs[128];
  int tid = threadIdx.x;
  int jc = blockIdx.y;
  if (tid < 128) {
    float s = 0.f;
#pragma unroll
    for (int mc = 0; mc < 16; ++mc) s += cpart[(size_t)mc * 1024 + jc * 128 + tid];
    combs[tid] = s;
  }
  __syncthreads();
  int n = blockIdx.x * 256 + tid;
  float s = 0.f;
  for (int i = 0; i < 128; ++i)
    s += combs[i] * oh_w[(size_t)(jc * 128 + i) * D_IN + n];
  ppart[(size_t)jc * D_IN + n] = s;
}

__global__ __launch_bounds__(256) void k_pred_red(
    const float* __restrict__ ppart, const float* __restrict__ oh_b,
    float* __restrict__ pred) {
  int n = blockIdx.x * 256 + threadIdx.x;
  float s = oh_b[n];
#pragma unroll
  for (int jc = 0; jc < 8; ++jc) s += ppart[(size_t)jc * D_IN + n];
  pred[n] = s;
}

// ---------------- launcher ----------------
extern "C" void kernel_launch(void* const* d_in, const int* in_sizes, int n_in,
                              void* d_out, int out_size, void* d_ws, size_t ws_size,
                              hipStream_t stream) {
  const float* x     = (const float*)d_in[0];
  const float* h_re  = (const float*)d_in[1];
  const float* h_im  = (const float*)d_in[2];
  const float* ea_wr = (const float*)d_in[3];
  const float* ea_br = (const float*)d_in[4];
  const float* ea_wi = (const float*)d_in[5];
  const float* ea_bi = (const float*)d_in[6];
  const float* eg_wr = (const float*)d_in[7];
  const float* eg_br = (const float*)d_in[8];
  const float* eg_wi = (const float*)d_in[9];
  const float* eg_bi = (const float*)d_in[10];
  const float* gz_w  = (const float*)d_in[11];
  const float* gz_b  = (const float*)d_in[12];
  const float* gr_w  = (const float*)d_in[13];
  const float* gr_b  = (const float*)d_in[14];
  const float* ghr_w = (const float*)d_in[15];
  const float* ghr_b = (const float*)d_in[16];
  const float* ghi_w = (const float*)d_in[17];
  const float* ghi_b = (const float*)d_in[18];
  const float* oh_w  = (const float*)d_in[19];
  const float* oh_b  = (const float*)d_in[20];
  const int*   step  = (const int*)d_in[21];

  float* out = (float*)d_out;
  float* pred_out  = out;
  float* meanT_out = out + 512;
  float* nhre_out  = out + 513;
  float* nhim_out  = out + 513 + N_CELLS * D_HID;

  char* p = (char*)d_ws;
  auto carve = [&](size_t bytes) { char* r = p; p += (bytes + 255) & ~(size_t)255; return r; };
  short* wdrT   = (short*)carve(512 * 1024 * 2);
  short* wdiT   = (short*)carve(512 * 1024 * 2);
  short* wdnT   = (short*)carve(512 * 1024 * 2);
  short* gzwT   = (short*)carve(1024 * 1536 * 2);
  short* grwT   = (short*)carve(1024 * 1536 * 2);
  short* ghrwT  = (short*)carve(1024 * 1536 * 2);
  short* ghiwT  = (short*)carve(1024 * 1536 * 2);
  short* hbre   = (short*)carve(2048 * 1024 * 2);
  short* hbim   = (short*)carve(2048 * 1024 * 2);
  short* gatesA = (short*)carve((size_t)2048 * 1536 * 2);
  short* candAre= (short*)carve((size_t)2048 * 1536 * 2);
  short* candAim= (short*)carve((size_t)2048 * 1536 * 2);
  float* ore    = (float*)carve(2048 * 512 * 4);
  float* oim    = (float*)carve(2048 * 512 * 4);
  float* zbuf   = (float*)carve((size_t)2048 * 1024 * 4);
  float* bias_re= (float*)carve(512 * 4);
  float* bias_im= (float*)carve(512 * 4);
  float* bpartr = (float*)carve(8 * 512 * 4);
  float* bparti = (float*)carve(8 * 512 * 4);
  float* tens   = (float*)carve(2048 * 4);
  float* fpart  = (float*)carve(2 * 64 * 1024 * 4);
  float* fsre   = (float*)carve(8 * 1024 * 4);
  float* fsim   = (float*)carve(8 * 1024 * 4);
  float* gre    = (float*)carve(1024 * 4);
  float* gim    = (float*)carve(1024 * 4);
  float* wsoft  = (float*)carve(2048 * 4);
  float* cpart  = (float*)carve(16 * 1024 * 4);
  float* ppart  = (float*)carve(8 * 512 * 4);

  hipLaunchKernelGGL(k_transpose_all, dim3(48, 32, 5), dim3(256), 0, stream,
                     gz_w, gr_w, ghr_w, ghi_w, gzwT, grwT, ghrwT, ghiwT,
                     ea_wr, eg_wr, ea_wi, eg_wi, wdrT, wdiT, wdnT);
  hipLaunchKernelGGL(k_prep_h, dim3(2048), dim3(256), 0, stream,
                     h_re, h_im, hbre, hbim, gatesA, tens);
  hipLaunchKernelGGL(k_bias_part, dim3(2, 8), dim3(256), 0, stream,
                     x, ea_wr, ea_wi, eg_wr, eg_wi, bpartr, bparti);
  hipLaunchKernelGGL(k_bias_red, dim3(2), dim3(256), 0, stream,
                     bpartr, bparti, ea_br, ea_bi, eg_br, eg_bi, bias_re, bias_im);
  hipLaunchKernelGGL(k_engine, dim3(16, 16), dim3(256), 0, stream,
                     hbre, hbim, wdrT, wdiT, wdnT, bias_re, bias_im,
                     ore, oim, gatesA, candAre, candAim, tens);
  hipLaunchKernelGGL(k_gates, dim3(16, 16, 2), dim3(256), 0, stream,
                     gatesA, gzwT, grwT, gz_w, gz_b, gr_w, gr_b, tens,
                     h_re, h_im, zbuf, candAre, candAim);
  hipLaunchKernelGGL(k_cand, dim3(16, 16, 2), dim3(256), 0, stream,
                     candAre, candAim, ghrwT, ghiwT, ghr_b, ghi_b, ghr_w,
                     tens, zbuf, h_re, h_im, nhre_out, nhim_out);
  hipLaunchKernelGGL(k_fsum_part, dim3(64, 2), dim3(256), 0, stream,
                     nhre_out, nhim_out, fpart);
  hipLaunchKernelGGL(k_fsum_red, dim3(4, 2), dim3(256), 0, stream,
                     fpart, fsre, fsim, gre, gim);
  hipLaunchKernelGGL(k_sync, dim3((N_CELLS * D_HID) / 256), dim3(256), 0, stream,
                     nhre_out, nhim_out, fsre, fsim, gre, gim, step);
  hipLaunchKernelGGL(k_stats, dim3(1), dim3(1024), 0, stream, tens, wsoft, meanT_out);
  hipLaunchKernelGGL(k_comb_part, dim3(4, 16), dim3(256), 0, stream,
                     ore, oim, wsoft, cpart);
  hipLaunchKernelGGL(k_pred_part, dim3(2, 8), dim3(256), 0, stream, cpart, oh_w, ppart);
  hipLaunchKernelGGL(k_pred_red, dim3(2), dim3(256), 0, stream, ppart, oh_b, pred_out);
}

// Round 6
// 277.304 us; speedup vs baseline: 1.4239x; 1.4239x over previous
//
#include <hip/hip_runtime.h>
#include <math.h>

#define N_CELLS 2048
#define D_IN 512
#define D_HID 1024
#define D_OUT 512

typedef __attribute__((ext_vector_type(8))) short bf16x8;
typedef __attribute__((ext_vector_type(4))) float f32x4;
typedef __attribute__((ext_vector_type(4))) short short4v;

#define MFMA16(a, b, c) __builtin_amdgcn_mfma_f32_16x16x32_bf16(a, b, c, 0, 0, 0)

__device__ __forceinline__ short f2bf(float f) {
  union { float f; unsigned u; } v; v.f = f;
  unsigned r = (v.u + 0x7FFFu + ((v.u >> 16) & 1u)) >> 16;
  return (short)r;
}

__device__ __forceinline__ void gl_lds16(const void* g, void* l) {
  __builtin_amdgcn_global_load_lds(
      (const __attribute__((address_space(1))) void*)g,
      (__attribute__((address_space(3))) void*)l, 16, 0, 0);
}

// ---------------- prep: all weight transposes in ONE launch ----------------
__global__ __launch_bounds__(256) void k_transpose_all(
    const float* __restrict__ w0, const float* __restrict__ w1,
    const float* __restrict__ w2, const float* __restrict__ w3,
    short* __restrict__ t0, short* __restrict__ t1,
    short* __restrict__ t2, short* __restrict__ t3,
    const float* __restrict__ ea_wr, const float* __restrict__ eg_wr,
    const float* __restrict__ ea_wi, const float* __restrict__ eg_wi,
    short* __restrict__ wdrT, short* __restrict__ wdiT, short* __restrict__ wdnT) {
  const int k0 = blockIdx.x * 32, n0 = blockIdx.y * 32;
  const int c = threadIdx.x & 31, r4 = threadIdx.x >> 5;
  if (blockIdx.z < 4) {
    const float* w = (blockIdx.z == 0) ? w0 : (blockIdx.z == 1) ? w1
                   : (blockIdx.z == 2) ? w2 : w3;
    short* wT = (blockIdx.z == 0) ? t0 : (blockIdx.z == 1) ? t1
              : (blockIdx.z == 2) ? t2 : t3;
    __shared__ float t[32][33];
#pragma unroll
    for (int i = 0; i < 4; ++i) {
      int kl = r4 * 4 + i;
      int k = k0 + kl;
      int srcrow = (k < 512) ? k : k + 1;
      t[kl][c] = w[(size_t)srcrow * D_HID + n0 + c];
    }
    __syncthreads();
#pragma unroll
    for (int i = 0; i < 4; ++i) {
      int nl = r4 * 4 + i;
      wT[(size_t)(n0 + nl) * 1536 + k0 + c] = f2bf(t[c][nl]);
    }
  } else {
    if (blockIdx.x >= 32 || blockIdx.y >= 16) return;
    __shared__ float tr[32][33], ti[32][33];
#pragma unroll
    for (int i = 0; i < 4; ++i) {
      int kl = r4 * 4 + i;
      int src = (512 + k0 + kl) * D_OUT + n0 + c;
      tr[kl][c] = ea_wr[src] - eg_wr[src];
      ti[kl][c] = ea_wi[src] - eg_wi[src];
    }
    __syncthreads();
#pragma unroll
    for (int i = 0; i < 4; ++i) {
      int nl = r4 * 4 + i;
      int dst = (n0 + nl) * D_HID + k0 + c;
      float dr = tr[c][nl], di = ti[c][nl];
      wdrT[dst] = f2bf(dr);
      wdiT[dst] = f2bf(di);
      wdnT[dst] = f2bf(-di);
    }
  }
}

// h fp32 -> bf16 + |h| into gatesA cols 512..1535 ; also zero tens
__global__ __launch_bounds__(256) void k_prep_h(
    const float* __restrict__ h_re, const float* __restrict__ h_im,
    short* __restrict__ hbre, short* __restrict__ hbim, short* __restrict__ gatesA,
    float* __restrict__ tens) {
  if (threadIdx.x == 0) tens[blockIdx.x] = 0.f;
  int idx4 = (blockIdx.x * 256 + threadIdx.x) * 4;
  int m = idx4 >> 10, n = idx4 & 1023;
  float4 hr = *(const float4*)&h_re[idx4];
  float4 hi = *(const float4*)&h_im[idx4];
  short4v br, bi, bm;
  br.x = f2bf(hr.x); br.y = f2bf(hr.y); br.z = f2bf(hr.z); br.w = f2bf(hr.w);
  bi.x = f2bf(hi.x); bi.y = f2bf(hi.y); bi.z = f2bf(hi.z); bi.w = f2bf(hi.w);
  bm.x = f2bf(sqrtf(hr.x * hr.x + hi.x * hi.x));
  bm.y = f2bf(sqrtf(hr.y * hr.y + hi.y * hi.y));
  bm.z = f2bf(sqrtf(hr.z * hr.z + hi.z * hi.z));
  bm.w = f2bf(sqrtf(hr.w * hr.w + hi.w * hi.w));
  *(short4v*)&hbre[idx4] = br;
  *(short4v*)&hbim[idx4] = bi;
  *(short4v*)&gatesA[(size_t)m * 1536 + 512 + n] = bm;
}

// ---------------- bias from x: split-K two-stage ----------------
__global__ __launch_bounds__(256) void k_bias_part(
    const float* __restrict__ x,
    const float* __restrict__ ea_wr, const float* __restrict__ ea_wi,
    const float* __restrict__ eg_wr, const float* __restrict__ eg_wi,
    float* __restrict__ bpartr, float* __restrict__ bparti) {
  int n = blockIdx.x * 256 + threadIdx.x;
  int kc = blockIdx.y;
  float sr = 0.f, si = 0.f;
  for (int i = 0; i < 64; ++i) {
    int k = kc * 64 + i;
    float xv = x[k];
    int idx = k * D_OUT + n;
    sr += xv * (ea_wr[idx] - eg_wr[idx]);
    si += xv * (ea_wi[idx] - eg_wi[idx]);
  }
  bpartr[kc * D_OUT + n] = sr;
  bparti[kc * D_OUT + n] = si;
}

__global__ __launch_bounds__(256) void k_bias_red(
    const float* __restrict__ bpartr, const float* __restrict__ bparti,
    const float* __restrict__ ea_br, const float* __restrict__ ea_bi,
    const float* __restrict__ eg_br, const float* __restrict__ eg_bi,
    float* __restrict__ bias_re, float* __restrict__ bias_im) {
  int n = blockIdx.x * 256 + threadIdx.x;
  float sr = 0.f, si = 0.f;
#pragma unroll
  for (int kc = 0; kc < 8; ++kc) { sr += bpartr[kc * D_OUT + n]; si += bparti[kc * D_OUT + n]; }
  float brd = ea_br[n] - eg_br[n];
  float bid = ea_bi[n] - eg_bi[n];
  bias_re[n] = sr + brd - bid;
  bias_im[n] = si + brd + bid;
}

// ---------------- MFMA GEMM 1: complex engine (tile 64x32, BK=64) ----------------
__global__ __launch_bounds__(256) void k_engine(
    const short* __restrict__ hbre, const short* __restrict__ hbim,
    const short* __restrict__ wdrT, const short* __restrict__ wdiT,
    const short* __restrict__ wdnT,
    const float* __restrict__ bias_re, const float* __restrict__ bias_im,
    float* __restrict__ ore, float* __restrict__ oim,
    short* __restrict__ gatesA, short* __restrict__ candAre, short* __restrict__ candAim,
    float* __restrict__ tens) {
  __shared__ short Ar[2 * 64 * 32], Ai[2 * 64 * 32];
  __shared__ short Brs[2 * 32 * 32], Bis[2 * 32 * 32], Bns[2 * 32 * 32];
  const int m0 = blockIdx.x * 64, n0 = blockIdx.y * 32;
  const int tid = threadIdx.x;
  const int wid = tid >> 6, lane = tid & 63;
  const int quad = lane >> 4, lcol = lane & 15;
  const int wm = wid * 16;
  f32x4 accre[2], accim[2];
#pragma unroll
  for (int nt = 0; nt < 2; ++nt) {
    accre[nt] = (f32x4){0.f, 0.f, 0.f, 0.f};
    accim[nt] = (f32x4){0.f, 0.f, 0.f, 0.f};
  }
  for (int k0 = 0; k0 < D_HID; k0 += 64) {
    if (k0) __syncthreads();
#pragma unroll
    for (int i = 0; i < 2; ++i) {
      int c = i * 256 + tid;  // 0..511
      int kh = c >> 8, row = (c >> 2) & 63, kq = c & 3;
      size_t g = (size_t)(m0 + row) * D_HID + k0 + kh * 32 + kq * 8;
      gl_lds16(hbre + g, &Ar[c * 8]);
      gl_lds16(hbim + g, &Ai[c * 8]);
    }
    {
      int c = tid;  // 0..255
      int kh = c >> 7, row = (c >> 2) & 31, kq = c & 3;
      size_t g = (size_t)(n0 + row) * D_HID + k0 + kh * 32 + kq * 8;
      gl_lds16(wdrT + g, &Brs[c * 8]);
      gl_lds16(wdiT + g, &Bis[c * 8]);
      gl_lds16(wdnT + g, &Bns[c * 8]);
    }
    __syncthreads();
#pragma unroll
    for (int kh = 0; kh < 2; ++kh) {
      bf16x8 ar, ai, br[2], bi[2], bn[2];
      int aoff = kh * 2048 + (wm + lcol) * 32 + quad * 8;
      ar = *(const bf16x8*)&Ar[aoff];
      ai = *(const bf16x8*)&Ai[aoff];
#pragma unroll
      for (int nt = 0; nt < 2; ++nt) {
        int boff = kh * 1024 + (nt * 16 + lcol) * 32 + quad * 8;
        br[nt] = *(const bf16x8*)&Brs[boff];
        bi[nt] = *(const bf16x8*)&Bis[boff];
        bn[nt] = *(const bf16x8*)&Bns[boff];
      }
#pragma unroll
      for (int nt = 0; nt < 2; ++nt) {
        accre[nt] = MFMA16(ar, br[nt], accre[nt]);
        accre[nt] = MFMA16(ai, bn[nt], accre[nt]);
        accim[nt] = MFMA16(ar, bi[nt], accim[nt]);
        accim[nt] = MFMA16(ai, br[nt], accim[nt]);
      }
    }
  }
#pragma unroll
  for (int r = 0; r < 4; ++r) {
    int m = m0 + wm + quad * 4 + r;
    float t = 0.f;
#pragma unroll
    for (int nt = 0; nt < 2; ++nt) {
      int n = n0 + nt * 16 + lcol;
      float cre = accre[nt][r] + bias_re[n];
      float cim = accim[nt][r] + bias_im[n];
      t += cre * cre + cim * cim;
      ore[(size_t)m * D_OUT + n] = cre;
      oim[(size_t)m * D_OUT + n] = cim;
      gatesA[(size_t)m * 1536 + n] = f2bf(sqrtf(cre * cre + cim * cim));
      candAre[(size_t)m * 1536 + n] = f2bf(cre);
      candAim[(size_t)m * 1536 + n] = f2bf(cim);
    }
#pragma unroll
    for (int off = 1; off < 16; off <<= 1) t += __shfl_xor(t, off);
    if (lcol == 0) atomicAdd(&tens[m], t * (1.f / 512.f));
  }
}

// ---------------- MFMA GEMM 2: gates (z/r via blockIdx.z), tile 64x64, BK=64 ----
// grid (32,16,2) = 1024 blocks; 4 waves in 2x2; wave tile 32x32 = 2x2 frags.
__global__ __launch_bounds__(256) void k_gates(
    const short* __restrict__ gatesA,
    const short* __restrict__ gzwT, const short* __restrict__ grwT,
    const float* __restrict__ gz_w, const float* __restrict__ gz_b,
    const float* __restrict__ gr_w, const float* __restrict__ gr_b,
    const float* __restrict__ tens,
    const float* __restrict__ h_re, const float* __restrict__ h_im,
    float* __restrict__ zbuf,
    short* __restrict__ candAre, short* __restrict__ candAim) {
  __shared__ short As[2 * 64 * 32];
  __shared__ short Bs[2 * 64 * 32];
  const int is_z = (blockIdx.z == 0);
  const short* Bt = is_z ? gzwT : grwT;
  const int m0 = blockIdx.x * 64, n0 = blockIdx.y * 64;
  const int tid = threadIdx.x;
  const int wid = tid >> 6, lane = tid & 63;
  const int quad = lane >> 4, lcol = lane & 15;
  const int wm = (wid >> 1) * 32, wn = (wid & 1) * 32;
  f32x4 acc[2][2];
#pragma unroll
  for (int mt = 0; mt < 2; ++mt)
#pragma unroll
    for (int nt = 0; nt < 2; ++nt) acc[mt][nt] = (f32x4){0.f, 0.f, 0.f, 0.f};
  for (int k0 = 0; k0 < 1536; k0 += 64) {
    if (k0) __syncthreads();
#pragma unroll
    for (int i = 0; i < 2; ++i) {
      int c = i * 256 + tid;  // 0..511
      int kh = c >> 8, row = (c >> 2) & 63, kq = c & 3;
      gl_lds16(gatesA + (size_t)(m0 + row) * 1536 + k0 + kh * 32 + kq * 8, &As[c * 8]);
      gl_lds16(Bt + (size_t)(n0 + row) * 1536 + k0 + kh * 32 + kq * 8, &Bs[c * 8]);
    }
    __syncthreads();
#pragma unroll
    for (int kh = 0; kh < 2; ++kh) {
      bf16x8 a[2], b[2];
#pragma unroll
      for (int mt = 0; mt < 2; ++mt)
        a[mt] = *(const bf16x8*)&As[kh * 2048 + (wm + mt * 16 + lcol) * 32 + quad * 8];
#pragma unroll
      for (int nt = 0; nt < 2; ++nt)
        b[nt] = *(const bf16x8*)&Bs[kh * 2048 + (wn + nt * 16 + lcol) * 32 + quad * 8];
#pragma unroll
      for (int mt = 0; mt < 2; ++mt)
#pragma unroll
        for (int nt = 0; nt < 2; ++nt)
          acc[mt][nt] = MFMA16(a[mt], b[nt], acc[mt][nt]);
    }
  }
#pragma unroll
  for (int mt = 0; mt < 2; ++mt)
#pragma unroll
    for (int nt = 0; nt < 2; ++nt)
#pragma unroll
      for (int r = 0; r < 4; ++r) {
        int m = m0 + wm + mt * 16 + quad * 4 + r;
        int n = n0 + wn + nt * 16 + lcol;
        float tv = tens[m];
        if (is_z) {
          float zp = acc[mt][nt][r] + gz_b[n] + tv * gz_w[(size_t)512 * D_HID + n];
          zbuf[(size_t)m * D_HID + n] = 1.f / (1.f + expf(-zp));
        } else {
          float rp = acc[mt][nt][r] + gr_b[n] + tv * gr_w[(size_t)512 * D_HID + n];
          float rr = 1.f / (1.f + expf(-rp));
          candAre[(size_t)m * 1536 + 512 + n] = f2bf(rr * h_re[(size_t)m * D_HID + n]);
          candAim[(size_t)m * 1536 + 512 + n] = f2bf(rr * h_im[(size_t)m * D_HID + n]);
        }
      }
}

// ---------------- MFMA GEMM 3: candidate + GRU blend, tile 64x64, BK=64 ----------------
__global__ __launch_bounds__(256) void k_cand(
    const short* __restrict__ candAre, const short* __restrict__ candAim,
    const short* __restrict__ ghrwT, const short* __restrict__ ghiwT,
    const float* __restrict__ ghr_b, const float* __restrict__ ghi_b,
    const float* __restrict__ ghr_w,
    const float* __restrict__ tens, const float* __restrict__ zbuf,
    const float* __restrict__ h_re, const float* __restrict__ h_im,
    float* __restrict__ nhre, float* __restrict__ nhim) {
  __shared__ short As[2 * 64 * 32];
  __shared__ short Bs[2 * 64 * 32];
  const int is_re = (blockIdx.z == 0);
  const short* A = is_re ? candAre : candAim;
  const short* Bt = is_re ? ghrwT : ghiwT;
  const float* bias = is_re ? ghr_b : ghi_b;
  const float* h = is_re ? h_re : h_im;
  float* outp = is_re ? nhre : nhim;
  const int m0 = blockIdx.x * 64, n0 = blockIdx.y * 64;
  const int tid = threadIdx.x;
  const int wid = tid >> 6, lane = tid & 63;
  const int quad = lane >> 4, lcol = lane & 15;
  const int wm = (wid >> 1) * 32, wn = (wid & 1) * 32;
  f32x4 acc[2][2];
#pragma unroll
  for (int mt = 0; mt < 2; ++mt)
#pragma unroll
    for (int nt = 0; nt < 2; ++nt) acc[mt][nt] = (f32x4){0.f, 0.f, 0.f, 0.f};
  for (int k0 = 0; k0 < 1536; k0 += 64) {
    if (k0) __syncthreads();
#pragma unroll
    for (int i = 0; i < 2; ++i) {
      int c = i * 256 + tid;
      int kh = c >> 8, row = (c >> 2) & 63, kq = c & 3;
      gl_lds16(A + (size_t)(m0 + row) * 1536 + k0 + kh * 32 + kq * 8, &As[c * 8]);
      gl_lds16(Bt + (size_t)(n0 + row) * 1536 + k0 + kh * 32 + kq * 8, &Bs[c * 8]);
    }
    __syncthreads();
#pragma unroll
    for (int kh = 0; kh < 2; ++kh) {
      bf16x8 a[2], b[2];
#pragma unroll
      for (int mt = 0; mt < 2; ++mt)
        a[mt] = *(const bf16x8*)&As[kh * 2048 + (wm + mt * 16 + lcol) * 32 + quad * 8];
#pragma unroll
      for (int nt = 0; nt < 2; ++nt)
        b[nt] = *(const bf16x8*)&Bs[kh * 2048 + (wn + nt * 16 + lcol) * 32 + quad * 8];
#pragma unroll
      for (int mt = 0; mt < 2; ++mt)
#pragma unroll
        for (int nt = 0; nt < 2; ++nt)
          acc[mt][nt] = MFMA16(a[mt], b[nt], acc[mt][nt]);
    }
  }
#pragma unroll
  for (int mt = 0; mt < 2; ++mt)
#pragma unroll
    for (int nt = 0; nt < 2; ++nt)
#pragma unroll
      for (int r = 0; r < 4; ++r) {
        int m = m0 + wm + mt * 16 + quad * 4 + r;
        int n = n0 + wn + nt * 16 + lcol;
        float pre = acc[mt][nt][r] + bias[n];
        if (is_re) pre += tens[m] * ghr_w[(size_t)512 * D_HID + n];
        float cand = tanhf(pre);
        float z = zbuf[(size_t)m * D_HID + n];
        float hv = h[(size_t)m * D_HID + n];
        outp[(size_t)m * D_HID + n] = (1.f - z) * hv + z * cand;
      }
}

// ---------------- faction sync: two-stage ----------------
__global__ __launch_bounds__(256) void k_fsum_part(
    const float* __restrict__ nhre, const float* __restrict__ nhim,
    float* __restrict__ fpart) {
  int f = blockIdx.x >> 3, rc = blockIdx.x & 7, comp = blockIdx.y;
  const float* src = comp ? nhim : nhre;
  int row0 = f * 256 + rc * 32;
#pragma unroll
  for (int nc = 0; nc < 4; ++nc) {
    int n = nc * 256 + threadIdx.x;
    float s = 0.f;
    const float* base = src + (size_t)row0 * D_HID + n;
    for (int j = 0; j < 32; ++j) s += base[(size_t)j * D_HID];
    fpart[((size_t)comp * 64 + blockIdx.x) * D_HID + n] = s;
  }
}

__global__ __launch_bounds__(256) void k_fsum_red(
    const float* __restrict__ fpart,
    float* __restrict__ fsre, float* __restrict__ fsim,
    float* __restrict__ gre, float* __restrict__ gim) {
  int n = blockIdx.x * 256 + threadIdx.x;
  int comp = blockIdx.y;
  float* fs = comp ? fsim : fsre;
  float* g = comp ? gim : gre;
  float gsum = 0.f;
#pragma unroll
  for (int f = 0; f < 8; ++f) {
    float sf = 0.f;
#pragma unroll
    for (int rc = 0; rc < 8; ++rc)
      sf += fpart[((size_t)comp * 64 + f * 8 + rc) * D_HID + n];
    fs[f * D_HID + n] = sf;
    gsum += sf;
  }
  g[n] = gsum * (1.f / 2048.f);
}

__global__ __launch_bounds__(256) void k_sync(
    float* __restrict__ nhre, float* __restrict__ nhim,
    const float* __restrict__ fsre, const float* __restrict__ fsim,
    const float* __restrict__ gre, const float* __restrict__ gim,
    const int* __restrict__ step) {
  int idx = blockIdx.x * 256 + threadIdx.x;
  int m = idx >> 10, n = idx & 1023;
  int f = m >> 8;
  float vr = nhre[idx], vi = nhim[idx];
  vr = 0.85f * vr + 0.15f * (fsre[f * D_HID + n] * (1.f / 256.f));
  vi = 0.85f * vi + 0.15f * (fsim[f * D_HID + n] * (1.f / 256.f));
  if (step[0] > 5 && (m & 255) < 64) {
    vr = 0.85f * vr + 0.15f * gre[n];
    vi = 0.85f * vi + 0.15f * gim[n];
  }
  nhre[idx] = vr;
  nhim[idx] = vi;
}

// ---------------- softmax stats ----------------
__global__ __launch_bounds__(1024) void k_stats(
    const float* __restrict__ tens, float* __restrict__ wsoft,
    float* __restrict__ meanT_out) {
  __shared__ float red[16];
  __shared__ float s_max, s_sum;
  int tid = threadIdx.x;
  int wid = tid >> 6, lane = tid & 63;
  float a = tens[tid], b = tens[tid + 1024];
  float mx = fmaxf(a, b);
  for (int off = 32; off; off >>= 1) mx = fmaxf(mx, __shfl_down(mx, off));
  if (lane == 0) red[wid] = mx;
  __syncthreads();
  if (tid == 0) {
    float m2 = red[0];
    for (int i = 1; i < 16; ++i) m2 = fmaxf(m2, red[i]);
    s_max = m2;
  }
  __syncthreads();
  float mxv = s_max;
  float ea = expf(a - mxv), eb = expf(b - mxv);
  float se = ea + eb;
  for (int off = 32; off; off >>= 1) se += __shfl_down(se, off);
  __syncthreads();
  if (lane == 0) red[wid] = se;
  __syncthreads();
  if (tid == 0) {
    float s2 = 0.f;
    for (int i = 0; i < 16; ++i) s2 += red[i];
    s_sum = s2;
  }
  __syncthreads();
  float inv = 1.f / s_sum;
  wsoft[tid] = ea * inv;
  wsoft[tid + 1024] = eb * inv;
  float st = a + b;
  for (int off = 32; off; off >>= 1) st += __shfl_down(st, off);
  __syncthreads();
  if (lane == 0) red[wid] = st;
  __syncthreads();
  if (tid == 0) {
    float s2 = 0.f;
    for (int i = 0; i < 16; ++i) s2 += red[i];
    meanT_out[0] = s2 * (1.f / 2048.f);
  }
}

// ---------------- combine stage1 ----------------
__global__ __launch_bounds__(256) void k_comb_part(
    const float* __restrict__ ore, const float* __restrict__ oim,
    const float* __restrict__ wsoft, float* __restrict__ cpart) {
  int j = blockIdx.x * 256 + threadIdx.x;
  int mc = blockIdx.y;
  const float* src = (j < 512) ? ore : oim;
  int col = j & 511;
  float s = 0.f;
  for (int i = 0; i < 128; ++i) {
    int m = mc * 128 + i;
    s += wsoft[m] * src[(size_t)m * D_OUT + col];
  }
  cpart[(size_t)mc * 1024 + j] = s;
}

// ---------------- pred stage1 (comb reduction fused in) ----------------
__global__ __launch_bounds__(256) void k_pred_part(
    const float* __restrict__ cpart, const float* __restrict__ oh_w,
    float* __restrict__ ppart) {
  __shared__ float combs[128];
  int tid = threadIdx.x;
  int jc = blockIdx.y;
  if (tid < 128) {
    float s = 0.f;
#pragma unroll
    for (int mc = 0; mc < 16; ++mc) s += cpart[(size_t)mc * 1024 + jc * 128 + tid];
    combs[tid] = s;
  }
  __syncthreads();
  int n = blockIdx.x * 256 + tid;
  float s = 0.f;
  for (int i = 0; i < 128; ++i)
    s += combs[i] * oh_w[(size_t)(jc * 128 + i) * D_IN + n];
  ppart[(size_t)jc * D_IN + n] = s;
}

__global__ __launch_bounds__(256) void k_pred_red(
    const float* __restrict__ ppart, const float* __restrict__ oh_b,
    float* __restrict__ pred) {
  int n = blockIdx.x * 256 + threadIdx.x;
  float s = oh_b[n];
#pragma unroll
  for (int jc = 0; jc < 8; ++jc) s += ppart[(size_t)jc * D_IN + n];
  pred[n] = s;
}

// ---------------- launcher ----------------
extern "C" void kernel_launch(void* const* d_in, const int* in_sizes, int n_in,
                              void* d_out, int out_size, void* d_ws, size_t ws_size,
                              hipStream_t stream) {
  const float* x     = (const float*)d_in[0];
  const float* h_re  = (const float*)d_in[1];
  const float* h_im  = (const float*)d_in[2];
  const float* ea_wr = (const float*)d_in[3];
  const float* ea_br = (const float*)d_in[4];
  const float* ea_wi = (const float*)d_in[5];
  const float* ea_bi = (const float*)d_in[6];
  const float* eg_wr = (const float*)d_in[7];
  const float* eg_br = (const float*)d_in[8];
  const float* eg_wi = (const float*)d_in[9];
  const float* eg_bi = (const float*)d_in[10];
  const float* gz_w  = (const float*)d_in[11];
  const float* gz_b  = (const float*)d_in[12];
  const float* gr_w  = (const float*)d_in[13];
  const float* gr_b  = (const float*)d_in[14];
  const float* ghr_w = (const float*)d_in[15];
  const float* ghr_b = (const float*)d_in[16];
  const float* ghi_w = (const float*)d_in[17];
  const float* ghi_b = (const float*)d_in[18];
  const float* oh_w  = (const float*)d_in[19];
  const float* oh_b  = (const float*)d_in[20];
  const int*   step  = (const int*)d_in[21];

  float* out = (float*)d_out;
  float* pred_out  = out;
  float* meanT_out = out + 512;
  float* nhre_out  = out + 513;
  float* nhim_out  = out + 513 + N_CELLS * D_HID;

  char* p = (char*)d_ws;
  auto carve = [&](size_t bytes) { char* r = p; p += (bytes + 255) & ~(size_t)255; return r; };
  short* wdrT   = (short*)carve(512 * 1024 * 2);
  short* wdiT   = (short*)carve(512 * 1024 * 2);
  short* wdnT   = (short*)carve(512 * 1024 * 2);
  short* gzwT   = (short*)carve(1024 * 1536 * 2);
  short* grwT   = (short*)carve(1024 * 1536 * 2);
  short* ghrwT  = (short*)carve(1024 * 1536 * 2);
  short* ghiwT  = (short*)carve(1024 * 1536 * 2);
  short* hbre   = (short*)carve(2048 * 1024 * 2);
  short* hbim   = (short*)carve(2048 * 1024 * 2);
  short* gatesA = (short*)carve((size_t)2048 * 1536 * 2);
  short* candAre= (short*)carve((size_t)2048 * 1536 * 2);
  short* candAim= (short*)carve((size_t)2048 * 1536 * 2);
  float* ore    = (float*)carve(2048 * 512 * 4);
  float* oim    = (float*)carve(2048 * 512 * 4);
  float* zbuf   = (float*)carve((size_t)2048 * 1024 * 4);
  float* bias_re= (float*)carve(512 * 4);
  float* bias_im= (float*)carve(512 * 4);
  float* bpartr = (float*)carve(8 * 512 * 4);
  float* bparti = (float*)carve(8 * 512 * 4);
  float* tens   = (float*)carve(2048 * 4);
  float* fpart  = (float*)carve(2 * 64 * 1024 * 4);
  float* fsre   = (float*)carve(8 * 1024 * 4);
  float* fsim   = (float*)carve(8 * 1024 * 4);
  float* gre    = (float*)carve(1024 * 4);
  float* gim    = (float*)carve(1024 * 4);
  float* wsoft  = (float*)carve(2048 * 4);
  float* cpart  = (float*)carve(16 * 1024 * 4);
  float* ppart  = (float*)carve(8 * 512 * 4);

  hipLaunchKernelGGL(k_transpose_all, dim3(48, 32, 5), dim3(256), 0, stream,
                     gz_w, gr_w, ghr_w, ghi_w, gzwT, grwT, ghrwT, ghiwT,
                     ea_wr, eg_wr, ea_wi, eg_wi, wdrT, wdiT, wdnT);
  hipLaunchKernelGGL(k_prep_h, dim3(2048), dim3(256), 0, stream,
                     h_re, h_im, hbre, hbim, gatesA, tens);
  hipLaunchKernelGGL(k_bias_part, dim3(2, 8), dim3(256), 0, stream,
                     x, ea_wr, ea_wi, eg_wr, eg_wi, bpartr, bparti);
  hipLaunchKernelGGL(k_bias_red, dim3(2), dim3(256), 0, stream,
                     bpartr, bparti, ea_br, ea_bi, eg_br, eg_bi, bias_re, bias_im);
  hipLaunchKernelGGL(k_engine, dim3(32, 16), dim3(256), 0, stream,
                     hbre, hbim, wdrT, wdiT, wdnT, bias_re, bias_im,
                     ore, oim, gatesA, candAre, candAim, tens);
  hipLaunchKernelGGL(k_gates, dim3(32, 16, 2), dim3(256), 0, stream,
                     gatesA, gzwT, grwT, gz_w, gz_b, gr_w, gr_b, tens,
                     h_re, h_im, zbuf, candAre, candAim);
  hipLaunchKernelGGL(k_cand, dim3(32, 16, 2), dim3(256), 0, stream,
                     candAre, candAim, ghrwT, ghiwT, ghr_b, ghi_b, ghr_w,
                     tens, zbuf, h_re, h_im, nhre_out, nhim_out);
  hipLaunchKernelGGL(k_fsum_part, dim3(64, 2), dim3(256), 0, stream,
                     nhre_out, nhim_out, fpart);
  hipLaunchKernelGGL(k_fsum_red, dim3(4, 2), dim3(256), 0, stream,
                     fpart, fsre, fsim, gre, gim);
  hipLaunchKernelGGL(k_sync, dim3((N_CELLS * D_HID) / 256), dim3(256), 0, stream,
                     nhre_out, nhim_out, fsre, fsim, gre, gim, step);
  hipLaunchKernelGGL(k_stats, dim3(1), dim3(1024), 0, stream, tens, wsoft, meanT_out);
  hipLaunchKernelGGL(k_comb_part, dim3(4, 16), dim3(256), 0, stream,
                     ore, oim, wsoft, cpart);
  hipLaunchKernelGGL(k_pred_part, dim3(2, 8), dim3(256), 0, stream, cpart, oh_w, ppart);
  hipLaunchKernelGGL(k_pred_red, dim3(2), dim3(256), 0, stream, ppart, oh_b, pred_out);
}